// Round 1
// baseline (1131.182 us; speedup 1.0000x reference)
//
#include <hip/hip_runtime.h>

// LinearAttention (fast-transformers, phi = elu+1), fp32 baseline.
// B=8 S=4096 D=512 H=8 DH=64. Pipeline:
//   1) Qf/Kf/V = act(x@W + b)   (3x SGEMM, phi fused for q,k)
//   2) KV[b,h] = Kf^T @ V, Ksum[b,h] = sum_s Kf   (per-(b,h) reduction)
//   3) attn = Z * (Qf @ KV), Z = 1/(Qf.Ksum + eps)
//   4) out = attn @ Wo + bo     (SGEMM)
// ws layout: Qf 64MB | Kf 64MB | V 64MB | KV 1MB | Ksum 16KB ; attn reuses Kf.

constexpr int Bb = 8;
constexpr int Ss = 4096;
constexpr int Dd = 512;
constexpr int Hh = 8;
constexpr int DHh = 64;
constexpr int Mtot = Bb * Ss;  // 32768
constexpr float EPSF = 1e-6f;

// ---------------- SGEMM: C = act(A @ W + bias) ----------------
// A:[M,512] row-major, W:[512,512] row-major, C:[M,512].
// 128x128 block tile, BK=16, 256 threads, 8x8 micro-tile (4+4 split).
__global__ __launch_bounds__(256) void sgemm_bias_act(
    const float* __restrict__ A, const float* __restrict__ W,
    const float* __restrict__ bias, float* __restrict__ C, int act)
{
  constexpr int K = 512, N = 512, BK = 16;
  __shared__ float As[BK][128];  // As[k][m]
  __shared__ float Bs[BK][128];  // Bs[k][n]
  const int tid = threadIdx.x;
  const int tx = tid & 15, ty = tid >> 4;
  const int row0 = blockIdx.x * 128;
  const int col0 = blockIdx.y * 128;

  float acc[8][8];
#pragma unroll
  for (int i = 0; i < 8; ++i)
#pragma unroll
    for (int j = 0; j < 8; ++j) acc[i][j] = 0.f;

  for (int k0 = 0; k0 < K; k0 += BK) {
    // stage A tile (128 rows x 16 k) -> As[k][m] (transposed for compute)
#pragma unroll
    for (int l = 0; l < 2; ++l) {
      const int idx = tid + l * 256;         // 0..511
      const int m = idx >> 2, kq = idx & 3;  // row, k-quad
      const float4 a = *reinterpret_cast<const float4*>(
          &A[(size_t)(row0 + m) * K + (k0 + kq * 4)]);
      As[kq * 4 + 0][m] = a.x;
      As[kq * 4 + 1][m] = a.y;
      As[kq * 4 + 2][m] = a.z;
      As[kq * 4 + 3][m] = a.w;
    }
    // stage B tile (16 k x 128 n) -> Bs[k][n]
#pragma unroll
    for (int l = 0; l < 2; ++l) {
      const int idx = tid + l * 256;
      const int kr = idx >> 5, nq = idx & 31;
      const float4 w = *reinterpret_cast<const float4*>(
          &W[(size_t)(k0 + kr) * N + (col0 + nq * 4)]);
      *reinterpret_cast<float4*>(&Bs[kr][nq * 4]) = w;
    }
    __syncthreads();
#pragma unroll
    for (int kk = 0; kk < BK; ++kk) {
      const float4 a0 = *reinterpret_cast<const float4*>(&As[kk][ty * 4]);
      const float4 a1 = *reinterpret_cast<const float4*>(&As[kk][64 + ty * 4]);
      const float4 b0 = *reinterpret_cast<const float4*>(&Bs[kk][tx * 4]);
      const float4 b1 = *reinterpret_cast<const float4*>(&Bs[kk][64 + tx * 4]);
      const float av[8] = {a0.x, a0.y, a0.z, a0.w, a1.x, a1.y, a1.z, a1.w};
      const float bv[8] = {b0.x, b0.y, b0.z, b0.w, b1.x, b1.y, b1.z, b1.w};
#pragma unroll
      for (int i = 0; i < 8; ++i)
#pragma unroll
        for (int j = 0; j < 8; ++j) acc[i][j] = fmaf(av[i], bv[j], acc[i][j]);
    }
    __syncthreads();
  }

  // epilogue: bias (+ phi), vectorized stores
#pragma unroll
  for (int i = 0; i < 8; ++i) {
    const int r = row0 + ((i < 4) ? (ty * 4 + i) : (64 + ty * 4 + i - 4));
#pragma unroll
    for (int jh = 0; jh < 2; ++jh) {
      const int c = col0 + ((jh == 0) ? tx * 4 : 64 + tx * 4);
      float o[4];
#pragma unroll
      for (int j = 0; j < 4; ++j) o[j] = acc[i][jh * 4 + j] + bias[c + j];
      if (act) {  // phi(x) = elu(x)+1 = x+1 (x>0) else exp(x)
#pragma unroll
        for (int j = 0; j < 4; ++j) o[j] = (o[j] > 0.f) ? (o[j] + 1.f) : __expf(o[j]);
      }
      const float4 ov = {o[0], o[1], o[2], o[3]};
      *reinterpret_cast<float4*>(&C[(size_t)r * N + c]) = ov;
    }
  }
}

// ---------------- KV reduction: KV[b,h] = Kf^T @ V, Ksum = sum_s Kf ------
// One block per (b,h); LDS-tiled 64 rows of S at a time.
__global__ __launch_bounds__(256) void kv_reduce(
    const float* __restrict__ Kf, const float* __restrict__ V,
    float* __restrict__ KV, float* __restrict__ Ksum)
{
  const int bh = blockIdx.x;  // b*8+h
  const int b = bh >> 3, h = bh & 7;
  __shared__ float Ks[64][68];  // +4 pad keeps float4 alignment, breaks pow2 stride
  __shared__ float Vs[64][68];
  const int tid = threadIdx.x;
  const int dx = (tid >> 4) * 4;  // d micro-tile base
  const int mx = (tid & 15) * 4;  // m micro-tile base
  float acc[4][4];
#pragma unroll
  for (int i = 0; i < 4; ++i)
#pragma unroll
    for (int j = 0; j < 4; ++j) acc[i][j] = 0.f;
  float ksum_acc = 0.f;
  const size_t base = (size_t)b * Ss * Dd + (size_t)h * DHh;

  for (int s0 = 0; s0 < Ss; s0 += 64) {
#pragma unroll
    for (int l = 0; l < 4; ++l) {
      const int idx = tid + l * 256;  // 0..1023
      const int rr = idx >> 4, cq = idx & 15;
      const size_t g = base + (size_t)(s0 + rr) * Dd + cq * 4;
      *reinterpret_cast<float4*>(&Ks[rr][cq * 4]) =
          *reinterpret_cast<const float4*>(&Kf[g]);
      *reinterpret_cast<float4*>(&Vs[rr][cq * 4]) =
          *reinterpret_cast<const float4*>(&V[g]);
    }
    __syncthreads();
#pragma unroll 4
    for (int s = 0; s < 64; ++s) {
      const float4 kd = *reinterpret_cast<const float4*>(&Ks[s][dx]);
      const float4 vm = *reinterpret_cast<const float4*>(&Vs[s][mx]);
      const float ka[4] = {kd.x, kd.y, kd.z, kd.w};
      const float va[4] = {vm.x, vm.y, vm.z, vm.w};
#pragma unroll
      for (int i = 0; i < 4; ++i)
#pragma unroll
        for (int j = 0; j < 4; ++j) acc[i][j] = fmaf(ka[i], va[j], acc[i][j]);
    }
    if (tid < 64) {
#pragma unroll 8
      for (int s = 0; s < 64; ++s) ksum_acc += Ks[s][tid];
    }
    __syncthreads();
  }

#pragma unroll
  for (int i = 0; i < 4; ++i) {
    const float4 ov = {acc[i][0], acc[i][1], acc[i][2], acc[i][3]};
    *reinterpret_cast<float4*>(&KV[((size_t)bh * 64 + dx + i) * 64 + mx]) = ov;
  }
  if (tid < 64) Ksum[(size_t)bh * 64 + tid] = ksum_acc;
}

// ---------------- attn = Z * (Qf @ KV) ----------------
// One block = 64 rows x 1 head (64 cols). Z computed in-block from Ksum.
__global__ __launch_bounds__(256) void attn_combine(
    const float* __restrict__ Qf, const float* __restrict__ KV,
    const float* __restrict__ Ksum, float* __restrict__ Out)
{
  const int h = blockIdx.y;
  const int r0 = blockIdx.x * 64;  // global row
  const int b = r0 >> 12;          // r0 / 4096
  const int bh = b * Hh + h;
  __shared__ float Qs[64][68];
  __shared__ float KVs[64][68];
  __shared__ float Ksums[64];
  __shared__ float Zs[64];
  const int tid = threadIdx.x;

#pragma unroll
  for (int l = 0; l < 4; ++l) {
    const int idx = tid + l * 256;
    const int rr = idx >> 4, cq = idx & 15;
    *reinterpret_cast<float4*>(&Qs[rr][cq * 4]) = *reinterpret_cast<const float4*>(
        &Qf[(size_t)(r0 + rr) * Dd + h * DHh + cq * 4]);
    *reinterpret_cast<float4*>(&KVs[rr][cq * 4]) = *reinterpret_cast<const float4*>(
        &KV[((size_t)bh * 64 + rr) * 64 + cq * 4]);
  }
  if (tid < 64) Ksums[tid] = Ksum[(size_t)bh * 64 + tid];
  __syncthreads();

  if (tid < 64) {
    float z = 0.f;
#pragma unroll 8
    for (int d = 0; d < 64; ++d) z = fmaf(Qs[tid][d], Ksums[d], z);
    Zs[tid] = 1.f / (z + EPSF);
  }
  __syncthreads();

  const int rx = (tid >> 4) * 4, mx = (tid & 15) * 4;
  float acc[4][4];
#pragma unroll
  for (int i = 0; i < 4; ++i)
#pragma unroll
    for (int j = 0; j < 4; ++j) acc[i][j] = 0.f;

#pragma unroll 4
  for (int d = 0; d < 64; ++d) {
    const float4 vm = *reinterpret_cast<const float4*>(&KVs[d][mx]);
    const float va[4] = {vm.x, vm.y, vm.z, vm.w};
#pragma unroll
    for (int i = 0; i < 4; ++i) {
      const float q = Qs[rx + i][d];
#pragma unroll
      for (int j = 0; j < 4; ++j) acc[i][j] = fmaf(q, va[j], acc[i][j]);
    }
  }

#pragma unroll
  for (int i = 0; i < 4; ++i) {
    const float z = Zs[rx + i];
    const float4 ov = {acc[i][0] * z, acc[i][1] * z, acc[i][2] * z, acc[i][3] * z};
    *reinterpret_cast<float4*>(&Out[(size_t)(r0 + rx + i) * Dd + h * DHh + mx]) = ov;
  }
}

extern "C" void kernel_launch(void* const* d_in, const int* in_sizes, int n_in,
                              void* d_out, int out_size, void* d_ws, size_t ws_size,
                              hipStream_t stream) {
  const float* x  = (const float*)d_in[0];
  const float* Wq = (const float*)d_in[1];
  const float* bq = (const float*)d_in[2];
  const float* Wk = (const float*)d_in[3];
  const float* bk = (const float*)d_in[4];
  const float* Wv = (const float*)d_in[5];
  const float* bv = (const float*)d_in[6];
  const float* Wo = (const float*)d_in[7];
  const float* bo = (const float*)d_in[8];
  float* out = (float*)d_out;

  char* ws = (char*)d_ws;
  float* Qf   = (float*)(ws);                         // 64 MB
  float* Kf   = (float*)(ws + ((size_t)64 << 20));    // 64 MB
  float* Vv   = (float*)(ws + ((size_t)128 << 20));   // 64 MB
  float* KV   = (float*)(ws + ((size_t)192 << 20));   // 1 MB
  float* Ksum = (float*)(ws + ((size_t)193 << 20));   // 16 KB
  float* attn = Kf;  // Kf dead after kv_reduce; reuse region

  const dim3 gg(Mtot / 128, Dd / 128);  // 256 x 4
  sgemm_bias_act<<<gg, 256, 0, stream>>>(x, Wq, bq, Qf, 1);
  sgemm_bias_act<<<gg, 256, 0, stream>>>(x, Wk, bk, Kf, 1);
  sgemm_bias_act<<<gg, 256, 0, stream>>>(x, Wv, bv, Vv, 0);
  kv_reduce<<<64, 256, 0, stream>>>(Kf, Vv, KV, Ksum);
  attn_combine<<<dim3(Mtot / 64, Hh), 256, 0, stream>>>(Qf, KV, Ksum, attn);
  sgemm_bias_act<<<gg, 256, 0, stream>>>(attn, Wo, bo, out, 0);
}

// Round 2
// 468.802 us; speedup vs baseline: 2.4129x; 2.4129x over previous
//
#include <hip/hip_runtime.h>
#include <hip/hip_fp16.h>

// LinearAttention (phi = elu+1). B=8 S=4096 D=512 H=8 DH=64.
// Round 2: split-bf16 MFMA GEMMs (C = Ah*Bh + Ah*Bl + Al*Bh, fp32-grade accuracy),
// m97 structure: 128x128 tile, BK=32, global_load_lds w=16, 16x16x32 bf16 MFMA,
// XOR-swizzled LDS (2-way conflicts only). Qf/Kf/V stored fp16. kv_reduce 2-stage.
// ws (<=184 MB): [x_hi 32|x_lo 32|Wt_hi 2|Wt_lo 2|Qf 32|Kf 32|V 32|KVp 17|Ksp|KV|Ksum]
// attn_hi/lo reuse the x_hi/x_lo region (dead after QKV gemms).

constexpr int Ss = 4096;
constexpr int Dd = 512;
constexpr int Hh = 8;
constexpr int Mtot = 8 * 4096;  // 32768
constexpr float EPSF = 1e-6f;

typedef short v8s __attribute__((ext_vector_type(8)));
typedef float v4f __attribute__((ext_vector_type(4)));

__device__ __forceinline__ short f2bf(float f) {  // RNE fp32 -> bf16
  unsigned u = __float_as_uint(f);
  u += 0x7fff + ((u >> 16) & 1);
  return (short)(u >> 16);
}
__device__ __forceinline__ float bf2f(short s) {
  return __uint_as_float(((unsigned)(unsigned short)s) << 16);
}
__device__ __forceinline__ void async_cp16(const void* g, void* l) {
  __builtin_amdgcn_global_load_lds((__attribute__((address_space(1))) void*)g,
                                   (__attribute__((address_space(3))) void*)l, 16, 0, 0);
}

// ---------- weight prep: W[512][512] -> Wt[n][k] bf16 hi/lo (4 matrices) ----------
__global__ __launch_bounds__(256) void prep_w(
    const float* __restrict__ W0, const float* __restrict__ W1,
    const float* __restrict__ W2, const float* __restrict__ W3,
    short* __restrict__ Th, short* __restrict__ Tl)
{
  const float* W = (blockIdx.z == 0) ? W0 : (blockIdx.z == 1) ? W1
                  : (blockIdx.z == 2) ? W2 : W3;
  short* th = Th + (size_t)blockIdx.z * 512 * 512;
  short* tl = Tl + (size_t)blockIdx.z * 512 * 512;
  __shared__ float tile[32][33];
  const int t = threadIdx.x;
  const int tx = t & 31, ty = t >> 5;  // 32 x 8
  const int k0 = blockIdx.x * 32, n0 = blockIdx.y * 32;
#pragma unroll
  for (int r = 0; r < 32; r += 8)
    tile[ty + r][tx] = W[(size_t)(k0 + ty + r) * 512 + n0 + tx];
  __syncthreads();
#pragma unroll
  for (int r = 0; r < 32; r += 8) {
    const float v = tile[tx][ty + r];  // = W[k0+tx][n0+ty+r]
    const short h = f2bf(v);
    const short l = f2bf(v - bf2f(h));
    th[(size_t)(n0 + ty + r) * 512 + k0 + tx] = h;
    tl[(size_t)(n0 + ty + r) * 512 + k0 + tx] = l;
  }
}

// ---------- x split: fp32 -> bf16 hi/lo ----------
__global__ __launch_bounds__(256) void split_x(
    const float* __restrict__ X, short* __restrict__ H, short* __restrict__ L, int n4)
{
  const int i = blockIdx.x * 256 + threadIdx.x;
  if (i >= n4) return;
  const float4 x = reinterpret_cast<const float4*>(X)[i];
  short4 h, l;
  h.x = f2bf(x.x); l.x = f2bf(x.x - bf2f(h.x));
  h.y = f2bf(x.y); l.y = f2bf(x.y - bf2f(h.y));
  h.z = f2bf(x.z); l.z = f2bf(x.z - bf2f(h.z));
  h.w = f2bf(x.w); l.w = f2bf(x.w - bf2f(h.w));
  reinterpret_cast<short4*>(H)[i] = h;
  reinterpret_cast<short4*>(L)[i] = l;
}

// ---------- split-bf16 MFMA GEMM: C = act(A @ Bt^T + bias) ----------
// A(hi/lo): [M][512] bf16 row-major; Bt(hi/lo): [512][512] bf16 = W^T (n-major).
// mode 0: fp32 out, no act; mode 1: fp16 out, phi; mode 2: fp16 out, no act.
__global__ __launch_bounds__(256) void gemm_split(
    const short* __restrict__ Ah, const short* __restrict__ Al,
    const short* __restrict__ Bh, const short* __restrict__ Bl,
    const float* __restrict__ bias, float* __restrict__ Cf,
    __half* __restrict__ Ch, int mode)
{
  constexpr int K = 512;
  __shared__ short As_h[128 * 32], As_l[128 * 32], Bs_h[128 * 32], Bs_l[128 * 32];
  const int t = threadIdx.x;
  const int lane = t & 63;
  const int wv = t >> 6;
  const int wm = wv & 1, wn = wv >> 1;
  const int row0 = blockIdx.x * 128, col0 = blockIdx.y * 128;
  const int mr = lane & 15, kq = lane >> 4;

  v4f acc[4][4];
#pragma unroll
  for (int i = 0; i < 4; ++i)
#pragma unroll
    for (int j = 0; j < 4; ++j) acc[i][j] = (v4f){0.f, 0.f, 0.f, 0.f};

  const int srow = t >> 2;  // 0..63: staged row within 64-row half
  const int spq = t & 3;    // physical k-quad (8 bf16 = 16B)

  for (int k0 = 0; k0 < K; k0 += 32) {
    // stage 4 tiles (A hi/lo, B hi/lo), 128x32 bf16 each, via global_load_lds.
    // LDS layout: row-major [r][32] with XOR swizzle: physical quad p holds
    // logical quad q = p ^ ((r>>1)&3).
#pragma unroll
    for (int c = 0; c < 2; ++c) {
      const int m = c * 64 + srow;
      const int q = spq ^ ((m >> 1) & 3);
      const size_t ga = (size_t)(row0 + m) * K + k0 + q * 8;
      const size_t gb = (size_t)(col0 + m) * K + k0 + q * 8;
      const int lo = c * 2048 + wv * 512;  // wave-uniform LDS offset (shorts)
      async_cp16(Ah + ga, As_h + lo);
      async_cp16(Al + ga, As_l + lo);
      async_cp16(Bh + gb, Bs_h + lo);
      async_cp16(Bl + gb, Bs_l + lo);
    }
    __syncthreads();

    v8s fah[4], fal[4], fbh[4], fbl[4];
#pragma unroll
    for (int i = 0; i < 4; ++i) {
      const int ma = wm * 64 + i * 16 + mr;
      const int pa = kq ^ ((ma >> 1) & 3);
      fah[i] = *reinterpret_cast<const v8s*>(&As_h[ma * 32 + pa * 8]);
      fal[i] = *reinterpret_cast<const v8s*>(&As_l[ma * 32 + pa * 8]);
      const int nb = wn * 64 + i * 16 + mr;
      const int pb = kq ^ ((nb >> 1) & 3);
      fbh[i] = *reinterpret_cast<const v8s*>(&Bs_h[nb * 32 + pb * 8]);
      fbl[i] = *reinterpret_cast<const v8s*>(&Bs_l[nb * 32 + pb * 8]);
    }
#pragma unroll
    for (int i = 0; i < 4; ++i)
#pragma unroll
      for (int j = 0; j < 4; ++j) {
        acc[i][j] = __builtin_amdgcn_mfma_f32_16x16x32_bf16(fah[i], fbh[j], acc[i][j], 0, 0, 0);
        acc[i][j] = __builtin_amdgcn_mfma_f32_16x16x32_bf16(fah[i], fbl[j], acc[i][j], 0, 0, 0);
        acc[i][j] = __builtin_amdgcn_mfma_f32_16x16x32_bf16(fal[i], fbh[j], acc[i][j], 0, 0, 0);
      }
    __syncthreads();
  }

  // epilogue. C/D layout: col = lane&15 (n), row = kq*4 + reg (m).
#pragma unroll
  for (int j = 0; j < 4; ++j) {
    const int nc = col0 + wn * 64 + j * 16 + mr;
    const float bz = bias[nc];
#pragma unroll
    for (int i = 0; i < 4; ++i) {
      const int mbase = row0 + wm * 64 + i * 16 + kq * 4;
#pragma unroll
      for (int r = 0; r < 4; ++r) {
        float v = acc[i][j][r] + bz;
        if (mode == 1) v = (v > 0.f) ? (v + 1.f) : __expf(v);
        if (mode == 0) Cf[(size_t)(mbase + r) * 512 + nc] = v;
        else Ch[(size_t)(mbase + r) * 512 + nc] = __float2half(v);
      }
    }
  }
}

// ---------- KV stage 1: per (s-chunk, bh): partial Kf^T@V and sum Kf ----------
__global__ __launch_bounds__(256) void kv_stage1(
    const __half* __restrict__ Kf, const __half* __restrict__ V,
    float* __restrict__ KVp, float* __restrict__ Ksp)
{
  const int sc = blockIdx.x, bh = blockIdx.y;
  const int b = bh >> 3, h = bh & 7;
  __shared__ float Ks[64][68];
  __shared__ float Vs[64][68];
  const int tid = threadIdx.x;
  const int dx = (tid >> 4) * 4;
  const int mx = (tid & 15) * 4;
  float acc[4][4];
#pragma unroll
  for (int i = 0; i < 4; ++i)
#pragma unroll
    for (int j = 0; j < 4; ++j) acc[i][j] = 0.f;
  float ksum_acc = 0.f;
  const size_t base = (size_t)b * Ss * Dd + (size_t)h * 64;

  for (int s0 = sc * 256; s0 < sc * 256 + 256; s0 += 64) {
#pragma unroll
    for (int l = 0; l < 2; ++l) {
      const int idx = tid + l * 256;           // 0..511
      const int rr = idx >> 3, cq = idx & 7;   // row, 8-col group
      const size_t g = base + (size_t)(s0 + rr) * Dd + cq * 8;
      const __half2* k2 = reinterpret_cast<const __half2*>(Kf + g);
      const __half2* v2 = reinterpret_cast<const __half2*>(V + g);
#pragma unroll
      for (int u = 0; u < 4; ++u) {
        const float2 kf = __half22float2(k2[u]);
        const float2 vf = __half22float2(v2[u]);
        Ks[rr][cq * 8 + u * 2] = kf.x; Ks[rr][cq * 8 + u * 2 + 1] = kf.y;
        Vs[rr][cq * 8 + u * 2] = vf.x; Vs[rr][cq * 8 + u * 2 + 1] = vf.y;
      }
    }
    __syncthreads();
#pragma unroll 4
    for (int s = 0; s < 64; ++s) {
      const float4 kd = *reinterpret_cast<const float4*>(&Ks[s][dx]);
      const float4 vm = *reinterpret_cast<const float4*>(&Vs[s][mx]);
      const float ka[4] = {kd.x, kd.y, kd.z, kd.w};
      const float va[4] = {vm.x, vm.y, vm.z, vm.w};
#pragma unroll
      for (int i = 0; i < 4; ++i)
#pragma unroll
        for (int j = 0; j < 4; ++j) acc[i][j] = fmaf(ka[i], va[j], acc[i][j]);
    }
    if (tid < 64) {
#pragma unroll 8
      for (int s = 0; s < 64; ++s) ksum_acc += Ks[s][tid];
    }
    __syncthreads();
  }

  const size_t pb = (size_t)(sc * 64 + bh);
#pragma unroll
  for (int i = 0; i < 4; ++i) {
    const float4 ov = {acc[i][0], acc[i][1], acc[i][2], acc[i][3]};
    *reinterpret_cast<float4*>(&KVp[(pb * 64 + dx + i) * 64 + mx]) = ov;
  }
  if (tid < 64) Ksp[pb * 64 + tid] = ksum_acc;
}

// ---------- KV stage 2: sum 16 partials ----------
__global__ __launch_bounds__(256) void kv_stage2(
    const float* __restrict__ KVp, const float* __restrict__ Ksp,
    float* __restrict__ KV, float* __restrict__ Ksum)
{
  const int bh = blockIdx.x, t = threadIdx.x;
  for (int e = t; e < 4096; e += 256) {
    float s = 0.f;
#pragma unroll
    for (int sc = 0; sc < 16; ++sc) s += KVp[((size_t)(sc * 64 + bh) << 12) + e];
    KV[(size_t)bh * 4096 + e] = s;
  }
  if (t < 64) {
    float s = 0.f;
#pragma unroll
    for (int sc = 0; sc < 16; ++sc) s += Ksp[(size_t)(sc * 64 + bh) * 64 + t];
    Ksum[bh * 64 + t] = s;
  }
}

// ---------- attn = Z * (Qf @ KV), fused bf16 hi/lo split output ----------
__global__ __launch_bounds__(256) void attn_combine(
    const __half* __restrict__ Qf, const float* __restrict__ KV,
    const float* __restrict__ Ksum, short* __restrict__ Oh, short* __restrict__ Ol)
{
  const int h = blockIdx.y;
  const int r0 = blockIdx.x * 64;
  const int b = r0 >> 12;
  const int bh = b * Hh + h;
  __shared__ float Qs[64][68];
  __shared__ float KVs[64][68];
  __shared__ float Ksums[64];
  __shared__ float Zs[64];
  const int tid = threadIdx.x;

#pragma unroll
  for (int l = 0; l < 2; ++l) {
    const int idx = tid + l * 256;
    const int rr = idx >> 3, cq = idx & 7;
    const __half2* q2 = reinterpret_cast<const __half2*>(
        Qf + (size_t)(r0 + rr) * Dd + h * 64 + cq * 8);
#pragma unroll
    for (int u = 0; u < 4; ++u) {
      const float2 qf = __half22float2(q2[u]);
      Qs[rr][cq * 8 + u * 2] = qf.x; Qs[rr][cq * 8 + u * 2 + 1] = qf.y;
    }
  }
#pragma unroll
  for (int l = 0; l < 4; ++l) {
    const int idx = tid + l * 256;
    const int rr = idx >> 4, cq = idx & 15;
    *reinterpret_cast<float4*>(&KVs[rr][cq * 4]) = *reinterpret_cast<const float4*>(
        &KV[(size_t)bh * 4096 + rr * 64 + cq * 4]);
  }
  if (tid < 64) Ksums[tid] = Ksum[bh * 64 + tid];
  __syncthreads();

  if (tid < 64) {
    float z = 0.f;
#pragma unroll 8
    for (int d = 0; d < 64; ++d) z = fmaf(Qs[tid][d], Ksums[d], z);
    Zs[tid] = 1.f / (z + EPSF);
  }
  __syncthreads();

  const int rx = (tid >> 4) * 4, mx = (tid & 15) * 4;
  float acc[4][4];
#pragma unroll
  for (int i = 0; i < 4; ++i)
#pragma unroll
    for (int j = 0; j < 4; ++j) acc[i][j] = 0.f;

#pragma unroll 4
  for (int d = 0; d < 64; ++d) {
    const float4 vm = *reinterpret_cast<const float4*>(&KVs[d][mx]);
    const float va[4] = {vm.x, vm.y, vm.z, vm.w};
#pragma unroll
    for (int i = 0; i < 4; ++i) {
      const float q = Qs[rx + i][d];
#pragma unroll
      for (int j = 0; j < 4; ++j) acc[i][j] = fmaf(q, va[j], acc[i][j]);
    }
  }

#pragma unroll
  for (int i = 0; i < 4; ++i) {
    const float z = Zs[rx + i];
    short4 hv, lv;
    float o;
    o = acc[i][0] * z; hv.x = f2bf(o); lv.x = f2bf(o - bf2f(hv.x));
    o = acc[i][1] * z; hv.y = f2bf(o); lv.y = f2bf(o - bf2f(hv.y));
    o = acc[i][2] * z; hv.z = f2bf(o); lv.z = f2bf(o - bf2f(hv.z));
    o = acc[i][3] * z; hv.w = f2bf(o); lv.w = f2bf(o - bf2f(hv.w));
    const size_t off = (size_t)(r0 + rx + i) * Dd + h * 64 + mx;
    *reinterpret_cast<short4*>(&Oh[off]) = hv;
    *reinterpret_cast<short4*>(&Ol[off]) = lv;
  }
}

extern "C" void kernel_launch(void* const* d_in, const int* in_sizes, int n_in,
                              void* d_out, int out_size, void* d_ws, size_t ws_size,
                              hipStream_t stream) {
  const float* x  = (const float*)d_in[0];
  const float* Wq = (const float*)d_in[1];
  const float* bq = (const float*)d_in[2];
  const float* Wk = (const float*)d_in[3];
  const float* bk = (const float*)d_in[4];
  const float* Wv = (const float*)d_in[5];
  const float* bv = (const float*)d_in[6];
  const float* Wo = (const float*)d_in[7];
  const float* bo = (const float*)d_in[8];
  float* out = (float*)d_out;

  char* ws = (char*)d_ws;
  const size_t MB = (size_t)1 << 20;
  short*  x_hi  = (short*)(ws);              // 32 MB (later: attn_hi)
  short*  x_lo  = (short*)(ws + 32 * MB);    // 32 MB (later: attn_lo)
  short*  Wt_hi = (short*)(ws + 64 * MB);    // 2 MB (4 x 512x512)
  short*  Wt_lo = (short*)(ws + 66 * MB);    // 2 MB
  __half* Qf    = (__half*)(ws + 68 * MB);   // 32 MB
  __half* Kf    = (__half*)(ws + 100 * MB);  // 32 MB
  __half* Vv    = (__half*)(ws + 132 * MB);  // 32 MB
  float*  KVp   = (float*)(ws + 164 * MB);   // 17 MB (16x64x64x64 f32)
  float*  Ksp   = (float*)(ws + 181 * MB);   // 256 KB
  float*  KV    = (float*)(ws + 182 * MB);   // 1 MB
  float*  Ksum  = (float*)(ws + 183 * MB);   // 16 KB
  short*  attn_hi = x_hi;
  short*  attn_lo = x_lo;
  const size_t WSTEP = 512 * 512;

  prep_w<<<dim3(16, 16, 4), 256, 0, stream>>>(Wq, Wk, Wv, Wo, Wt_hi, Wt_lo);
  split_x<<<Mtot * Dd / 4 / 256, 256, 0, stream>>>(x, x_hi, x_lo, Mtot * Dd / 4);

  const dim3 gg(Mtot / 128, Dd / 128);  // 256 x 4
  gemm_split<<<gg, 256, 0, stream>>>(x_hi, x_lo, Wt_hi, Wt_lo, bq, nullptr, Qf, 1);
  gemm_split<<<gg, 256, 0, stream>>>(x_hi, x_lo, Wt_hi + WSTEP, Wt_lo + WSTEP, bk, nullptr, Kf, 1);
  gemm_split<<<gg, 256, 0, stream>>>(x_hi, x_lo, Wt_hi + 2 * WSTEP, Wt_lo + 2 * WSTEP, bv, nullptr, Vv, 2);

  kv_stage1<<<dim3(16, 64), 256, 0, stream>>>(Kf, Vv, KVp, Ksp);
  kv_stage2<<<64, 256, 0, stream>>>(KVp, Ksp, KV, Ksum);
  attn_combine<<<dim3(Mtot / 64, Hh), 256, 0, stream>>>(Qf, KV, Ksum, attn_hi, attn_lo);

  gemm_split<<<gg, 256, 0, stream>>>(attn_hi, attn_lo, Wt_hi + 3 * WSTEP, Wt_lo + 3 * WSTEP,
                                     bo, out, nullptr, 0);
}

// Round 4
// 432.861 us; speedup vs baseline: 2.6133x; 1.0830x over previous
//
#include <hip/hip_runtime.h>
#include <hip/hip_fp16.h>

// LinearAttention (phi = elu+1). B=8 S=4096 D=512 H=8 DH=64.
// Round 4: bisection round. Round 3 failed post-timing (replay divergence);
// this round = round 2 (fully verified) + ONE delta: fused QKV GEMM dispatch.
// All epilogues/attn/kv stages are round-2 verbatim (known post-timing-good).
// ws: [x_hi 32|x_lo 32|Wt_hi 2|Wt_lo 2|Qf 32|Kf 32|V 32|KVp 17|Ksp|KV|Ksum]
// attn_hi/lo reuse x_hi/x_lo (dead after QKV gemm).

constexpr int Ss = 4096;
constexpr int Dd = 512;
constexpr int Hh = 8;
constexpr int Mtot = 8 * 4096;  // 32768
constexpr float EPSF = 1e-6f;

typedef short v8s __attribute__((ext_vector_type(8)));
typedef float v4f __attribute__((ext_vector_type(4)));

__device__ __forceinline__ short f2bf(float f) {  // RNE fp32 -> bf16
  unsigned u = __float_as_uint(f);
  u += 0x7fff + ((u >> 16) & 1);
  return (short)(u >> 16);
}
__device__ __forceinline__ float bf2f(short s) {
  return __uint_as_float(((unsigned)(unsigned short)s) << 16);
}
__device__ __forceinline__ void async_cp16(const void* g, void* l) {
  __builtin_amdgcn_global_load_lds((__attribute__((address_space(1))) void*)g,
                                   (__attribute__((address_space(3))) void*)l, 16, 0, 0);
}

// ---------- weight prep: W[512][512] -> Wt[n][k] bf16 hi/lo (4 matrices) ----------
__global__ __launch_bounds__(256) void prep_w(
    const float* __restrict__ W0, const float* __restrict__ W1,
    const float* __restrict__ W2, const float* __restrict__ W3,
    short* __restrict__ Th, short* __restrict__ Tl)
{
  const float* W = (blockIdx.z == 0) ? W0 : (blockIdx.z == 1) ? W1
                  : (blockIdx.z == 2) ? W2 : W3;
  short* th = Th + (size_t)blockIdx.z * 512 * 512;
  short* tl = Tl + (size_t)blockIdx.z * 512 * 512;
  __shared__ float tile[32][33];
  const int t = threadIdx.x;
  const int tx = t & 31, ty = t >> 5;  // 32 x 8
  const int k0 = blockIdx.x * 32, n0 = blockIdx.y * 32;
#pragma unroll
  for (int r = 0; r < 32; r += 8)
    tile[ty + r][tx] = W[(size_t)(k0 + ty + r) * 512 + n0 + tx];
  __syncthreads();
#pragma unroll
  for (int r = 0; r < 32; r += 8) {
    const float v = tile[tx][ty + r];  // = W[k0+tx][n0+ty+r]
    const short h = f2bf(v);
    const short l = f2bf(v - bf2f(h));
    th[(size_t)(n0 + ty + r) * 512 + k0 + tx] = h;
    tl[(size_t)(n0 + ty + r) * 512 + k0 + tx] = l;
  }
}

// ---------- x split: fp32 -> bf16 hi/lo ----------
__global__ __launch_bounds__(256) void split_x(
    const float* __restrict__ X, short* __restrict__ H, short* __restrict__ L, int n4)
{
  const int i = blockIdx.x * 256 + threadIdx.x;
  if (i >= n4) return;
  const float4 x = reinterpret_cast<const float4*>(X)[i];
  short4 h, l;
  h.x = f2bf(x.x); l.x = f2bf(x.x - bf2f(h.x));
  h.y = f2bf(x.y); l.y = f2bf(x.y - bf2f(h.y));
  h.z = f2bf(x.z); l.z = f2bf(x.z - bf2f(h.z));
  h.w = f2bf(x.w); l.w = f2bf(x.w - bf2f(h.w));
  reinterpret_cast<short4*>(H)[i] = h;
  reinterpret_cast<short4*>(L)[i] = l;
}

// ---------- fused QKV split-bf16 MFMA GEMM (round-2 internals, direct stores) ----
// grid (Mtot/128, 12): y = mat*4 + colblock. phi for q,k; fp16 outputs.
__global__ __launch_bounds__(256) void gemm_qkv(
    const short* __restrict__ Ah, const short* __restrict__ Al,
    const short* __restrict__ Wth, const short* __restrict__ Wtl,
    const float* __restrict__ bq, const float* __restrict__ bk,
    const float* __restrict__ bv,
    __half* __restrict__ Qf, __half* __restrict__ Kf, __half* __restrict__ Vv)
{
  constexpr int K = 512;
  __shared__ short As_h[128 * 32], As_l[128 * 32], Bs_h[128 * 32], Bs_l[128 * 32];

  const int mat = blockIdx.y >> 2;
  const int col0 = (blockIdx.y & 3) * 128;
  const int row0 = blockIdx.x * 128;
  const short* Bh = Wth + (size_t)mat * K * 512;
  const short* Bl = Wtl + (size_t)mat * K * 512;
  const float* bias = (mat == 0) ? bq : (mat == 1) ? bk : bv;
  __half* Co = (mat == 0) ? Qf : (mat == 1) ? Kf : Vv;
  const int act = (mat < 2);

  const int t = threadIdx.x;
  const int lane = t & 63;
  const int wv = t >> 6;
  const int wm = wv & 1, wn = wv >> 1;
  const int mr = lane & 15, kq = lane >> 4;

  v4f acc[4][4];
#pragma unroll
  for (int i = 0; i < 4; ++i)
#pragma unroll
    for (int j = 0; j < 4; ++j) acc[i][j] = (v4f){0.f, 0.f, 0.f, 0.f};

  const int srow = t >> 2;
  const int spq = t & 3;

  for (int k0 = 0; k0 < K; k0 += 32) {
#pragma unroll
    for (int c = 0; c < 2; ++c) {
      const int m = c * 64 + srow;
      const int q = spq ^ ((m >> 1) & 3);
      const size_t ga = (size_t)(row0 + m) * K + k0 + q * 8;
      const size_t gb = (size_t)(col0 + m) * K + k0 + q * 8;
      const int lo = c * 2048 + wv * 512;
      async_cp16(Ah + ga, As_h + lo);
      async_cp16(Al + ga, As_l + lo);
      async_cp16(Bh + gb, Bs_h + lo);
      async_cp16(Bl + gb, Bs_l + lo);
    }
    __syncthreads();

    v8s fah[4], fal[4], fbh[4], fbl[4];
#pragma unroll
    for (int i = 0; i < 4; ++i) {
      const int ma = wm * 64 + i * 16 + mr;
      const int pa = kq ^ ((ma >> 1) & 3);
      fah[i] = *reinterpret_cast<const v8s*>(&As_h[ma * 32 + pa * 8]);
      fal[i] = *reinterpret_cast<const v8s*>(&As_l[ma * 32 + pa * 8]);
      const int nb = wn * 64 + i * 16 + mr;
      const int pb = kq ^ ((nb >> 1) & 3);
      fbh[i] = *reinterpret_cast<const v8s*>(&Bs_h[nb * 32 + pb * 8]);
      fbl[i] = *reinterpret_cast<const v8s*>(&Bs_l[nb * 32 + pb * 8]);
    }
#pragma unroll
    for (int i = 0; i < 4; ++i)
#pragma unroll
      for (int j = 0; j < 4; ++j) {
        acc[i][j] = __builtin_amdgcn_mfma_f32_16x16x32_bf16(fah[i], fbh[j], acc[i][j], 0, 0, 0);
        acc[i][j] = __builtin_amdgcn_mfma_f32_16x16x32_bf16(fah[i], fbl[j], acc[i][j], 0, 0, 0);
        acc[i][j] = __builtin_amdgcn_mfma_f32_16x16x32_bf16(fal[i], fbh[j], acc[i][j], 0, 0, 0);
      }
    __syncthreads();
  }

  // epilogue (round-2 verbatim pattern): direct fp16 stores.
  // C/D layout: col = lane&15 (n), row = kq*4 + reg (m).
#pragma unroll
  for (int j = 0; j < 4; ++j) {
    const int nc = col0 + wn * 64 + j * 16 + mr;
    const float bz = bias[nc];
#pragma unroll
    for (int i = 0; i < 4; ++i) {
      const int mbase = row0 + wm * 64 + i * 16 + kq * 4;
#pragma unroll
      for (int r = 0; r < 4; ++r) {
        float v = acc[i][j][r] + bz;
        if (act) v = (v > 0.f) ? (v + 1.f) : __expf(v);
        Co[(size_t)(mbase + r) * 512 + nc] = __float2half(v);
      }
    }
  }
}

// ---------- final GEMM (round-2 gemm_split, mode 0): out = attn @ Wo + bo ----
__global__ __launch_bounds__(256) void gemm_split(
    const short* __restrict__ Ah, const short* __restrict__ Al,
    const short* __restrict__ Bh, const short* __restrict__ Bl,
    const float* __restrict__ bias, float* __restrict__ Cf)
{
  constexpr int K = 512;
  __shared__ short As_h[128 * 32], As_l[128 * 32], Bs_h[128 * 32], Bs_l[128 * 32];
  const int t = threadIdx.x;
  const int lane = t & 63;
  const int wv = t >> 6;
  const int wm = wv & 1, wn = wv >> 1;
  const int row0 = blockIdx.x * 128, col0 = blockIdx.y * 128;
  const int mr = lane & 15, kq = lane >> 4;

  v4f acc[4][4];
#pragma unroll
  for (int i = 0; i < 4; ++i)
#pragma unroll
    for (int j = 0; j < 4; ++j) acc[i][j] = (v4f){0.f, 0.f, 0.f, 0.f};

  const int srow = t >> 2;
  const int spq = t & 3;

  for (int k0 = 0; k0 < K; k0 += 32) {
#pragma unroll
    for (int c = 0; c < 2; ++c) {
      const int m = c * 64 + srow;
      const int q = spq ^ ((m >> 1) & 3);
      const size_t ga = (size_t)(row0 + m) * K + k0 + q * 8;
      const size_t gb = (size_t)(col0 + m) * K + k0 + q * 8;
      const int lo = c * 2048 + wv * 512;
      async_cp16(Ah + ga, As_h + lo);
      async_cp16(Al + ga, As_l + lo);
      async_cp16(Bh + gb, Bs_h + lo);
      async_cp16(Bl + gb, Bs_l + lo);
    }
    __syncthreads();

    v8s fah[4], fal[4], fbh[4], fbl[4];
#pragma unroll
    for (int i = 0; i < 4; ++i) {
      const int ma = wm * 64 + i * 16 + mr;
      const int pa = kq ^ ((ma >> 1) & 3);
      fah[i] = *reinterpret_cast<const v8s*>(&As_h[ma * 32 + pa * 8]);
      fal[i] = *reinterpret_cast<const v8s*>(&As_l[ma * 32 + pa * 8]);
      const int nb = wn * 64 + i * 16 + mr;
      const int pb = kq ^ ((nb >> 1) & 3);
      fbh[i] = *reinterpret_cast<const v8s*>(&Bs_h[nb * 32 + pb * 8]);
      fbl[i] = *reinterpret_cast<const v8s*>(&Bs_l[nb * 32 + pb * 8]);
    }
#pragma unroll
    for (int i = 0; i < 4; ++i)
#pragma unroll
      for (int j = 0; j < 4; ++j) {
        acc[i][j] = __builtin_amdgcn_mfma_f32_16x16x32_bf16(fah[i], fbh[j], acc[i][j], 0, 0, 0);
        acc[i][j] = __builtin_amdgcn_mfma_f32_16x16x32_bf16(fah[i], fbl[j], acc[i][j], 0, 0, 0);
        acc[i][j] = __builtin_amdgcn_mfma_f32_16x16x32_bf16(fal[i], fbh[j], acc[i][j], 0, 0, 0);
      }
    __syncthreads();
  }

#pragma unroll
  for (int j = 0; j < 4; ++j) {
    const int nc = col0 + wn * 64 + j * 16 + mr;
    const float bz = bias[nc];
#pragma unroll
    for (int i = 0; i < 4; ++i) {
      const int mbase = row0 + wm * 64 + i * 16 + kq * 4;
#pragma unroll
      for (int r = 0; r < 4; ++r) Cf[(size_t)(mbase + r) * 512 + nc] = acc[i][j][r] + bz;
    }
  }
}

// ---------- KV stage 1 (round-2 verbatim): partial Kf^T@V and sum Kf ----------
__global__ __launch_bounds__(256) void kv_stage1(
    const __half* __restrict__ Kf, const __half* __restrict__ V,
    float* __restrict__ KVp, float* __restrict__ Ksp)
{
  const int sc = blockIdx.x, bh = blockIdx.y;
  const int b = bh >> 3, h = bh & 7;
  __shared__ float Ks[64][68];
  __shared__ float Vs[64][68];
  const int tid = threadIdx.x;
  const int dx = (tid >> 4) * 4;
  const int mx = (tid & 15) * 4;
  float acc[4][4];
#pragma unroll
  for (int i = 0; i < 4; ++i)
#pragma unroll
    for (int j = 0; j < 4; ++j) acc[i][j] = 0.f;
  float ksum_acc = 0.f;
  const size_t base = (size_t)b * Ss * Dd + (size_t)h * 64;

  for (int s0 = sc * 256; s0 < sc * 256 + 256; s0 += 64) {
#pragma unroll
    for (int l = 0; l < 2; ++l) {
      const int idx = tid + l * 256;
      const int rr = idx >> 3, cq = idx & 7;
      const size_t g = base + (size_t)(s0 + rr) * Dd + cq * 8;
      const __half2* k2 = reinterpret_cast<const __half2*>(Kf + g);
      const __half2* v2 = reinterpret_cast<const __half2*>(V + g);
#pragma unroll
      for (int u = 0; u < 4; ++u) {
        const float2 kf = __half22float2(k2[u]);
        const float2 vf = __half22float2(v2[u]);
        Ks[rr][cq * 8 + u * 2] = kf.x; Ks[rr][cq * 8 + u * 2 + 1] = kf.y;
        Vs[rr][cq * 8 + u * 2] = vf.x; Vs[rr][cq * 8 + u * 2 + 1] = vf.y;
      }
    }
    __syncthreads();
#pragma unroll 4
    for (int s = 0; s < 64; ++s) {
      const float4 kd = *reinterpret_cast<const float4*>(&Ks[s][dx]);
      const float4 vm = *reinterpret_cast<const float4*>(&Vs[s][mx]);
      const float ka[4] = {kd.x, kd.y, kd.z, kd.w};
      const float va[4] = {vm.x, vm.y, vm.z, vm.w};
#pragma unroll
      for (int i = 0; i < 4; ++i)
#pragma unroll
        for (int j = 0; j < 4; ++j) acc[i][j] = fmaf(ka[i], va[j], acc[i][j]);
    }
    if (tid < 64) {
#pragma unroll 8
      for (int s = 0; s < 64; ++s) ksum_acc += Ks[s][tid];
    }
    __syncthreads();
  }

  const size_t pb = (size_t)(sc * 64 + bh);
#pragma unroll
  for (int i = 0; i < 4; ++i) {
    const float4 ov = {acc[i][0], acc[i][1], acc[i][2], acc[i][3]};
    *reinterpret_cast<float4*>(&KVp[(pb * 64 + dx + i) * 64 + mx]) = ov;
  }
  if (tid < 64) Ksp[pb * 64 + tid] = ksum_acc;
}

// ---------- KV stage 2 (round-2 verbatim): sum 16 partials ----------
__global__ __launch_bounds__(256) void kv_stage2(
    const float* __restrict__ KVp, const float* __restrict__ Ksp,
    float* __restrict__ KV, float* __restrict__ Ksum)
{
  const int bh = blockIdx.x, t = threadIdx.x;
  for (int e = t; e < 4096; e += 256) {
    float s = 0.f;
#pragma unroll
    for (int sc = 0; sc < 16; ++sc) s += KVp[((size_t)(sc * 64 + bh) << 12) + e];
    KV[(size_t)bh * 4096 + e] = s;
  }
  if (t < 64) {
    float s = 0.f;
#pragma unroll
    for (int sc = 0; sc < 16; ++sc) s += Ksp[(size_t)(sc * 64 + bh) * 64 + t];
    Ksum[bh * 64 + t] = s;
  }
}

// ---------- attn (round-2 verbatim): Z * (Qf @ KV), bf16 hi/lo split out -----
__global__ __launch_bounds__(256) void attn_combine(
    const __half* __restrict__ Qf, const float* __restrict__ KV,
    const float* __restrict__ Ksum, short* __restrict__ Oh, short* __restrict__ Ol)
{
  const int h = blockIdx.y;
  const int r0 = blockIdx.x * 64;
  const int b = r0 >> 12;
  const int bh = b * Hh + h;
  __shared__ float Qs[64][68];
  __shared__ float KVs[64][68];
  __shared__ float Ksums[64];
  __shared__ float Zs[64];
  const int tid = threadIdx.x;

#pragma unroll
  for (int l = 0; l < 2; ++l) {
    const int idx = tid + l * 256;
    const int rr = idx >> 3, cq = idx & 7;
    const __half2* q2 = reinterpret_cast<const __half2*>(
        Qf + (size_t)(r0 + rr) * Dd + h * 64 + cq * 8);
#pragma unroll
    for (int u = 0; u < 4; ++u) {
      const float2 qf = __half22float2(q2[u]);
      Qs[rr][cq * 8 + u * 2] = qf.x; Qs[rr][cq * 8 + u * 2 + 1] = qf.y;
    }
  }
#pragma unroll
  for (int l = 0; l < 4; ++l) {
    const int idx = tid + l * 256;
    const int rr = idx >> 4, cq = idx & 15;
    *reinterpret_cast<float4*>(&KVs[rr][cq * 4]) = *reinterpret_cast<const float4*>(
        &KV[(size_t)bh * 4096 + rr * 64 + cq * 4]);
  }
  if (tid < 64) Ksums[tid] = Ksum[bh * 64 + tid];
  __syncthreads();

  if (tid < 64) {
    float z = 0.f;
#pragma unroll 8
    for (int d = 0; d < 64; ++d) z = fmaf(Qs[tid][d], Ksums[d], z);
    Zs[tid] = 1.f / (z + EPSF);
  }
  __syncthreads();

  const int rx = (tid >> 4) * 4, mx = (tid & 15) * 4;
  float acc[4][4];
#pragma unroll
  for (int i = 0; i < 4; ++i)
#pragma unroll
    for (int j = 0; j < 4; ++j) acc[i][j] = 0.f;

#pragma unroll 4
  for (int d = 0; d < 64; ++d) {
    const float4 vm = *reinterpret_cast<const float4*>(&KVs[d][mx]);
    const float va[4] = {vm.x, vm.y, vm.z, vm.w};
#pragma unroll
    for (int i = 0; i < 4; ++i) {
      const float q = Qs[rx + i][d];
#pragma unroll
      for (int j = 0; j < 4; ++j) acc[i][j] = fmaf(q, va[j], acc[i][j]);
    }
  }

#pragma unroll
  for (int i = 0; i < 4; ++i) {
    const float z = Zs[rx + i];
    short4 hv, lv;
    float o;
    o = acc[i][0] * z; hv.x = f2bf(o); lv.x = f2bf(o - bf2f(hv.x));
    o = acc[i][1] * z; hv.y = f2bf(o); lv.y = f2bf(o - bf2f(hv.y));
    o = acc[i][2] * z; hv.z = f2bf(o); lv.z = f2bf(o - bf2f(hv.z));
    o = acc[i][3] * z; hv.w = f2bf(o); lv.w = f2bf(o - bf2f(hv.w));
    const size_t off = (size_t)(r0 + rx + i) * Dd + h * 64 + mx;
    *reinterpret_cast<short4*>(&Oh[off]) = hv;
    *reinterpret_cast<short4*>(&Ol[off]) = lv;
  }
}

extern "C" void kernel_launch(void* const* d_in, const int* in_sizes, int n_in,
                              void* d_out, int out_size, void* d_ws, size_t ws_size,
                              hipStream_t stream) {
  const float* x  = (const float*)d_in[0];
  const float* Wq = (const float*)d_in[1];
  const float* bq = (const float*)d_in[2];
  const float* Wk = (const float*)d_in[3];
  const float* bk = (const float*)d_in[4];
  const float* Wv = (const float*)d_in[5];
  const float* bv = (const float*)d_in[6];
  const float* Wo = (const float*)d_in[7];
  const float* bo = (const float*)d_in[8];
  float* out = (float*)d_out;

  char* ws = (char*)d_ws;
  const size_t MB = (size_t)1 << 20;
  short*  x_hi  = (short*)(ws);              // 32 MB (later: attn_hi)
  short*  x_lo  = (short*)(ws + 32 * MB);    // 32 MB (later: attn_lo)
  short*  Wt_hi = (short*)(ws + 64 * MB);    // 2 MB (4 x 512x512)
  short*  Wt_lo = (short*)(ws + 66 * MB);    // 2 MB
  __half* Qf    = (__half*)(ws + 68 * MB);   // 32 MB
  __half* Kf    = (__half*)(ws + 100 * MB);  // 32 MB
  __half* Vv    = (__half*)(ws + 132 * MB);  // 32 MB
  float*  KVp   = (float*)(ws + 164 * MB);   // 17 MB
  float*  Ksp   = (float*)(ws + 181 * MB);   // 256 KB
  float*  KV    = (float*)(ws + 182 * MB);   // 1 MB
  float*  Ksum  = (float*)(ws + 183 * MB);   // 16 KB
  short*  attn_hi = x_hi;
  short*  attn_lo = x_lo;
  const size_t WSTEP = (size_t)512 * 512;

  prep_w<<<dim3(16, 16, 4), 256, 0, stream>>>(Wq, Wk, Wv, Wo, Wt_hi, Wt_lo);
  split_x<<<Mtot * Dd / 4 / 256, 256, 0, stream>>>(x, x_hi, x_lo, Mtot * Dd / 4);

  gemm_qkv<<<dim3(Mtot / 128, 12), 256, 0, stream>>>(
      x_hi, x_lo, Wt_hi, Wt_lo, bq, bk, bv, Qf, Kf, Vv);

  kv_stage1<<<dim3(16, 64), 256, 0, stream>>>(Kf, Vv, KVp, Ksp);
  kv_stage2<<<64, 256, 0, stream>>>(KVp, Ksp, KV, Ksum);
  attn_combine<<<dim3(Mtot / 64, Hh), 256, 0, stream>>>(Qf, KV, Ksum, attn_hi, attn_lo);

  gemm_split<<<dim3(Mtot / 128, 4), 256, 0, stream>>>(
      attn_hi, attn_lo, Wt_hi + 3 * WSTEP, Wt_lo + 3 * WSTEP, bo, out);
}